// Round 1
// baseline (107.798 us; speedup 1.0000x reference)
//
#include <hip/hip_runtime.h>
#include <math.h>

// S4D kernel materialization:
//   dt = exp(inv_dt[h]);  A = -exp(A_real) + i*A_imag;  dtA = dt*A
//   Cm = (B*C) * (exp(dtA)-1)/A          (complex, per h,n)
//   K[h,l] = 2 * Re( sum_n Cm[h,n] * exp(dtA[h,n] * l) )
//
// H=1024, N=64, CH=1, L=2048. Output (1,H,L) float32 = 8 MB.
// Compute-bound on transcendentals: per (n,l) one exp + one sincos.
// Strategy: 1 block per h; threads 0..63 precompute per-n params into LDS
// (broadcast reads later, conflict-free); each of 256 threads owns 8 l's.

#define HH 1024
#define NN 64
#define LPT 8          // l-values per thread (L=2048 / 256 threads)
#define LOG2E  1.4426950408889634f
#define INV2PI 0.15915494309189535f

__global__ __launch_bounds__(256) void s4d_vand_kernel(
    const float* __restrict__ A_real,
    const float* __restrict__ A_imag,
    const float* __restrict__ B,
    const float* __restrict__ C,
    const float* __restrict__ inv_dt,
    float* __restrict__ out,
    int L)
{
    __shared__ float4 params[NN];   // (re*log2e, im/2pi, 2*Cm.re, 2*Cm.im)

    const int h = blockIdx.x;
    const int t = threadIdx.x;

    if (t < NN) {
        const int n  = t;
        const int hn = h * NN + n;
        float Ar = A_real[hn];
        float Ai = A_imag[hn];
        float dt = expf(inv_dt[h]);          // rate = 1.0
        float are = -expf(Ar);               // Re(A) = -exp(A_real)
        float dre = dt * are;                // Re(dtA)  (<= 0)
        float dim = dt * Ai;                 // Im(dtA)
        // exp(dtA) - 1
        float er = expf(dre);
        float s, c;
        sincosf(dim, &s, &c);
        float em1r = er * c - 1.0f;
        float em1i = er * s;
        // (exp(dtA)-1)/A  via conj(A)/|A|^2
        float inv = 1.0f / (are * are + Ai * Ai);
        float zr = (em1r * are + em1i * Ai) * inv;
        float zi = (em1i * are - em1r * Ai) * inv;
        // Bc * Cc
        float br = B[2 * hn],  bi = B[2 * hn + 1];
        float Cr = C[2 * hn],  Ci = C[2 * hn + 1];
        float bcr = br * Cr - bi * Ci;
        float bci = br * Ci + bi * Cr;
        // Cm = (Bc*Cc) * z, fold in the final 2x
        float cmr = bcr * zr - bci * zi;
        float cmi = bcr * zi + bci * zr;
        params[n] = make_float4(dre * LOG2E, dim * INV2PI, 2.0f * cmr, 2.0f * cmi);
    }
    __syncthreads();

    float acc[LPT];
    float lf[LPT];
#pragma unroll
    for (int j = 0; j < LPT; ++j) {
        acc[j] = 0.0f;
        lf[j]  = (float)(t + 256 * j);
    }

#pragma unroll 4
    for (int n = 0; n < NN; ++n) {
        const float4 p = params[n];   // wave-uniform LDS read -> broadcast
#pragma unroll
        for (int j = 0; j < LPT; ++j) {
            float x = p.y * lf[j];            // angle in revolutions
            float f = x - floorf(x);          // exact range reduction
            float s = __builtin_amdgcn_sinf(f);   // sin(2*pi*f)
            float c = __builtin_amdgcn_cosf(f);   // cos(2*pi*f)
            float e = __builtin_amdgcn_exp2f(p.x * lf[j]);  // exp(re*l)
            // acc += e * (2Cr*c - 2Ci*s)
            acc[j] = fmaf(e, fmaf(-p.w, s, p.z * c), acc[j]);
        }
    }

#pragma unroll
    for (int j = 0; j < LPT; ++j) {
        int l = t + 256 * j;
        if (l < L) out[h * L + l] = acc[j];
    }
}

extern "C" void kernel_launch(void* const* d_in, const int* in_sizes, int n_in,
                              void* d_out, int out_size, void* d_ws, size_t ws_size,
                              hipStream_t stream) {
    const float* A_real = (const float*)d_in[0];
    const float* A_imag = (const float*)d_in[1];
    const float* B      = (const float*)d_in[2];
    const float* C      = (const float*)d_in[3];
    const float* inv_dt = (const float*)d_in[4];
    // d_in[5] is L on device; derive L on host from out_size (CH=1, H=1024)
    int L = out_size / HH;

    s4d_vand_kernel<<<HH, 256, 0, stream>>>(A_real, A_imag, B, C, inv_dt,
                                            (float*)d_out, L);
}

// Round 2
// 83.210 us; speedup vs baseline: 1.2955x; 1.2955x over previous
//
#include <hip/hip_runtime.h>
#include <math.h>

// S4D kernel materialization:
//   dt = exp(inv_dt[h]);  A = -exp(A_real) + i*A_imag;  dtA = dt*A
//   Cm = (B*C) * (exp(dtA)-1)/A          (complex, per h,n)
//   K[h,l] = 2 * Re( sum_n Cm[h,n] * exp(dtA[h,n] * l) )
//
// H=1024, N=64, CH=1, L=2048. Output (1,H,L) float32 = 8 MB.
//
// R2: replace per-(n,l) transcendentals with a geometric recurrence.
//   thread t owns l = t + 128*j (j=0..15, coalesced stores).
//   state_n(j=0) = 2*Cm_n * exp(dtA_n * t)          (3 trans, once per n per thread)
//   state_n     *= W_n = exp(dtA_n * 128)           (1 complex mul per step, from LDS)
//   acc[j] += Re(state)
// Inner cost: 5 regular VALU ops per (n,l) vs 36 cyc of trans+VALU before.
// n unrolled by 2 for two independent recurrence chains (ILP).

#define HH 1024
#define NN 64
#define TPB 128        // threads per block = one h per block
#define LPT 16         // 2048 / 128
#define LOG2E  1.4426950408889634f
#define INV2PI 0.15915494309189535f

__global__ __launch_bounds__(TPB) void s4d_recur_kernel(
    const float* __restrict__ A_real,
    const float* __restrict__ A_imag,
    const float* __restrict__ B,
    const float* __restrict__ C,
    const float* __restrict__ inv_dt,
    float* __restrict__ out,
    int L)
{
    __shared__ float4 pA[NN];   // (dre*log2e, dim/2pi, 2*Cm.re, 2*Cm.im)
    __shared__ float2 pW[NN];   // W = exp(dtA * TPB)

    const int h = blockIdx.x;
    const int t = threadIdx.x;

    if (t < NN) {
        const int n  = t;
        const int hn = h * NN + n;
        float Ar = A_real[hn];
        float Ai = A_imag[hn];
        float dt = expf(inv_dt[h]);          // rate = 1.0
        float are = -expf(Ar);               // Re(A) = -exp(A_real)
        float dre = dt * are;                // Re(dtA)  (<= 0)
        float dim = dt * Ai;                 // Im(dtA)
        // exp(dtA) - 1
        float er = expf(dre);
        float s, c;
        sincosf(dim, &s, &c);
        float em1r = er * c - 1.0f;
        float em1i = er * s;
        // (exp(dtA)-1)/A  via conj(A)/|A|^2
        float inv = 1.0f / (are * are + Ai * Ai);
        float zr = (em1r * are + em1i * Ai) * inv;
        float zi = (em1i * are - em1r * Ai) * inv;
        // Bc * Cc
        float br = B[2 * hn],  bi = B[2 * hn + 1];
        float Cr = C[2 * hn],  Ci = C[2 * hn + 1];
        float bcr = br * Cr - bi * Ci;
        float bci = br * Ci + bi * Cr;
        // Cm = (Bc*Cc) * z, fold in the final 2x
        float cmr = bcr * zr - bci * zi;
        float cmi = bcr * zi + bci * zr;

        float dreL = dre * LOG2E;
        float dimR = dim * INV2PI;
        // W = exp(dtA * TPB)
        float we = exp2f(dreL * (float)TPB);
        float wx = dimR * (float)TPB;
        float wf = wx - floorf(wx);
        float Wc, Ws;
        Wc = __builtin_amdgcn_cosf(wf);
        Ws = __builtin_amdgcn_sinf(wf);
        pA[n] = make_float4(dreL, dimR, 2.0f * cmr, 2.0f * cmi);
        pW[n] = make_float2(we * Wc, we * Ws);
    }
    __syncthreads();

    float acc[LPT];
#pragma unroll
    for (int j = 0; j < LPT; ++j) acc[j] = 0.0f;

    const float tf = (float)t;

    for (int n = 0; n < NN; n += 2) {
        const float4 a0 = pA[n];       // wave-uniform -> LDS broadcast
        const float4 a1 = pA[n + 1];
        const float2 w0 = pW[n];
        const float2 w1 = pW[n + 1];

        // chunk-start state: 2*Cm * exp(dtA * t)
        float e0 = __builtin_amdgcn_exp2f(a0.x * tf);
        float x0 = a0.y * tf;
        float f0 = x0 - floorf(x0);
        float c0 = __builtin_amdgcn_cosf(f0);
        float s0 = __builtin_amdgcn_sinf(f0);
        float er0 = e0 * c0, ei0 = e0 * s0;
        float sr0 = a0.z * er0 - a0.w * ei0;
        float si0 = a0.z * ei0 + a0.w * er0;

        float e1 = __builtin_amdgcn_exp2f(a1.x * tf);
        float x1 = a1.y * tf;
        float f1 = x1 - floorf(x1);
        float c1 = __builtin_amdgcn_cosf(f1);
        float s1 = __builtin_amdgcn_sinf(f1);
        float er1 = e1 * c1, ei1 = e1 * s1;
        float sr1 = a1.z * er1 - a1.w * ei1;
        float si1 = a1.z * ei1 + a1.w * er1;

#pragma unroll
        for (int j = 0; j < LPT; ++j) {
            acc[j] += sr0 + sr1;
            float nr0 = fmaf(sr0, w0.x, -si0 * w0.y);
            float ni0 = fmaf(sr0, w0.y,  si0 * w0.x);
            sr0 = nr0; si0 = ni0;
            float nr1 = fmaf(sr1, w1.x, -si1 * w1.y);
            float ni1 = fmaf(sr1, w1.y,  si1 * w1.x);
            sr1 = nr1; si1 = ni1;
        }
    }

#pragma unroll
    for (int j = 0; j < LPT; ++j) {
        out[h * L + j * TPB + t] = acc[j];
    }
}

extern "C" void kernel_launch(void* const* d_in, const int* in_sizes, int n_in,
                              void* d_out, int out_size, void* d_ws, size_t ws_size,
                              hipStream_t stream) {
    const float* A_real = (const float*)d_in[0];
    const float* A_imag = (const float*)d_in[1];
    const float* B      = (const float*)d_in[2];
    const float* C      = (const float*)d_in[3];
    const float* inv_dt = (const float*)d_in[4];
    int L = out_size / HH;   // 2048

    s4d_recur_kernel<<<HH, TPB, 0, stream>>>(A_real, A_imag, B, C, inv_dt,
                                             (float*)d_out, L);
}

// Round 3
// 78.936 us; speedup vs baseline: 1.3656x; 1.0542x over previous
//
#include <hip/hip_runtime.h>
#include <math.h>

// S4D kernel materialization:
//   dt = exp(inv_dt[h]);  A = -exp(A_real) + i*A_imag;  dtA = dt*A
//   Cm = (B*C) * (exp(dtA)-1)/A          (complex, per h,n)
//   K[h,l] = 2 * Re( sum_n Cm[h,n] * exp(dtA[h,n] * l) )
//
// H=1024, N=64, CH=1, L=2048. Output (1,H,L) float32 = 8 MB.
//
// R3: second-order REAL recurrence. x_j = Re(2Cm * exp(dtA*(t+128j)))
// satisfies x_{j+1} = 2Re(W)*x_j - |W|^2*x_{j-1} with W = exp(dtA*128).
// Inner step: 1 mul + 1 fma + 1 acc-add = 3 VALU ops per (n,l)
// (vs 5 for the complex recurrence in R2). n unrolled x4 -> 4 independent
// chains, dep latency (~8 cyc/step) hidden under 24 cyc issue per j-step.

#define HH 1024
#define NN 64
#define TPB 128        // one h per block; thread t owns l = t + 128*j
#define LPT 16         // 2048 / 128
#define LOG2E  1.4426950408889634f
#define INV2PI 0.15915494309189535f

__global__ __launch_bounds__(TPB) void s4d_recur2_kernel(
    const float* __restrict__ A_real,
    const float* __restrict__ A_imag,
    const float* __restrict__ B,
    const float* __restrict__ C,
    const float* __restrict__ inv_dt,
    float* __restrict__ out,
    int L)
{
    __shared__ float4 pA[NN];   // (dre*log2e, dim/2pi, 2*Cm.re, 2*Cm.im)
    __shared__ float4 pW[NN];   // (Wr, Wi, a=2*Wr, b=Wr^2+Wi^2)

    const int h = blockIdx.x;
    const int t = threadIdx.x;

    if (t < NN) {
        const int n  = t;
        const int hn = h * NN + n;
        float Ar = A_real[hn];
        float Ai = A_imag[hn];
        float dt = expf(inv_dt[h]);          // rate = 1.0
        float are = -expf(Ar);               // Re(A) = -exp(A_real)
        float dre = dt * are;                // Re(dtA)  (<= 0)
        float dim = dt * Ai;                 // Im(dtA)
        // exp(dtA) - 1
        float er = expf(dre);
        float s, c;
        sincosf(dim, &s, &c);
        float em1r = er * c - 1.0f;
        float em1i = er * s;
        // (exp(dtA)-1)/A  via conj(A)/|A|^2
        float inv = 1.0f / (are * are + Ai * Ai);
        float zr = (em1r * are + em1i * Ai) * inv;
        float zi = (em1i * are - em1r * Ai) * inv;
        // Bc * Cc
        float br = B[2 * hn],  bi = B[2 * hn + 1];
        float Cr = C[2 * hn],  Ci = C[2 * hn + 1];
        float bcr = br * Cr - bi * Ci;
        float bci = br * Ci + bi * Cr;
        // Cm = (Bc*Cc) * z, fold in the final 2x
        float cmr = bcr * zr - bci * zi;
        float cmi = bcr * zi + bci * zr;

        float dreL = dre * LOG2E;
        float dimR = dim * INV2PI;
        // W = exp(dtA * TPB)
        float we = exp2f(dreL * (float)TPB);
        float wx = dimR * (float)TPB;
        float wf = wx - floorf(wx);
        float Wc = __builtin_amdgcn_cosf(wf);
        float Ws = __builtin_amdgcn_sinf(wf);
        float Wr = we * Wc, Wi = we * Ws;
        pA[n] = make_float4(dreL, dimR, 2.0f * cmr, 2.0f * cmi);
        pW[n] = make_float4(Wr, Wi, 2.0f * Wr, Wr * Wr + Wi * Wi);
    }
    __syncthreads();

    float acc[LPT];
#pragma unroll
    for (int j = 0; j < LPT; ++j) acc[j] = 0.0f;

    const float tf = (float)t;

    for (int n = 0; n < NN; n += 4) {
        float xp[4], xc[4], aa[4], bb[4];
#pragma unroll
        for (int k = 0; k < 4; ++k) {
            const float4 p = pA[n + k];   // wave-uniform -> LDS broadcast
            const float4 w = pW[n + k];
            // z0 = 2*Cm * exp(dtA * t)
            float e = __builtin_amdgcn_exp2f(p.x * tf);
            float x = p.y * tf;
            float f = x - floorf(x);
            float c = __builtin_amdgcn_cosf(f);
            float s = __builtin_amdgcn_sinf(f);
            float er = e * c, ei = e * s;
            float sr = p.z * er - p.w * ei;   // x0 = Re(z0)
            float si = p.z * ei + p.w * er;
            xp[k] = sr;
            xc[k] = sr * w.x - si * w.y;      // x1 = Re(z0 * W)
            aa[k] = w.z;                      // 2*Re(W)
            bb[k] = w.w;                      // |W|^2
        }
        acc[0] += (xp[0] + xp[1]) + (xp[2] + xp[3]);
#pragma unroll
        for (int j = 1; j < LPT; ++j) {
#pragma unroll
            for (int k = 0; k < 4; ++k) {
                acc[j] += xc[k];
                float xn = fmaf(aa[k], xc[k], -bb[k] * xp[k]);
                xp[k] = xc[k];
                xc[k] = xn;
            }
        }
    }

#pragma unroll
    for (int j = 0; j < LPT; ++j) {
        out[h * L + j * TPB + t] = acc[j];
    }
}

extern "C" void kernel_launch(void* const* d_in, const int* in_sizes, int n_in,
                              void* d_out, int out_size, void* d_ws, size_t ws_size,
                              hipStream_t stream) {
    const float* A_real = (const float*)d_in[0];
    const float* A_imag = (const float*)d_in[1];
    const float* B      = (const float*)d_in[2];
    const float* C      = (const float*)d_in[3];
    const float* inv_dt = (const float*)d_in[4];
    int L = out_size / HH;   // 2048

    s4d_recur2_kernel<<<HH, TPB, 0, stream>>>(A_real, A_imag, B, C, inv_dt,
                                              (float*)d_out, L);
}